// Round 1
// baseline (315.176 us; speedup 1.0000x reference)
//
#include <hip/hip_runtime.h>
#include <math.h>

// TensorTrainGaussian likelihood, restructured:
//   u0 = softmax(wk0_logits); u_{m+1} = R_m(x_n) u_m;  out = log(sum(u_M) + EPS)
//   R_m[i,j] = exp( logW[m,i,j] + NormalLogProb(x[n,m]; mu[m,i,j], sigma[m,i,j]) )
//            = exp2( (A*x + B)*x + C )   with A,B,C precomputed per (m,i,j)
// A = -0.5/s^2*log2e, B = mu/s^2*log2e,
// C = (logW - log s - 0.5*log(2pi) - 0.5*mu^2/s^2)*log2e, s = softplus(pre_sigma)

#define TTG_N 32768
#define TTG_M 16
#define TTG_K 64

static constexpr float kHalfLog2Pi = 0.9189385332046727f;
static constexpr float kEps        = 2.220446049250313e-16f;
static constexpr float kLog2e      = 1.4426950408889634f;

#if defined(__has_builtin)
#if __has_builtin(__builtin_amdgcn_exp2f)
#define TTG_EXP2(x) __builtin_amdgcn_exp2f(x)
#else
#define TTG_EXP2(x) exp2f(x)
#endif
#else
#define TTG_EXP2(x) exp2f(x)
#endif

// ---------------- prep: wk0 = softmax(wk0_logits) ----------------
__global__ void ttg_prep_wk0(const float* __restrict__ logits,
                             float* __restrict__ wk0) {
  int i = threadIdx.x;  // 64 threads = 1 wave
  float l = logits[i];
  float mx = l;
  for (int d = 1; d < 64; d <<= 1) mx = fmaxf(mx, __shfl_xor(mx, d));
  float e = expf(l - mx);
  float s = e;
  for (int d = 1; d < 64; d <<= 1) s += __shfl_xor(s, d);
  wk0[i] = e / s;
}

// ---------------- prep: per-(m,i,j) Horner coefficients ----------------
// One wave per (m, j) column; lane = i. log_softmax over i (axis=1 of (M,K,K)).
// Output layout TRANSPOSED for the main kernel: P[((m*K + j)*3 + plane)*K + i]
__global__ void ttg_prep_params(const float* __restrict__ W,
                                const float* __restrict__ mu,
                                const float* __restrict__ ps,
                                float* __restrict__ P) {
  int b = blockIdx.x;
  int m = b >> 6;
  int j = b & 63;
  int i = threadIdx.x;
  int idx = (m * TTG_K + i) * TTG_K + j;  // [m][i][j]

  float w = W[idx];
  float mx = w;
  for (int d = 1; d < 64; d <<= 1) mx = fmaxf(mx, __shfl_xor(mx, d));
  float e = expf(w - mx);
  float s = e;
  for (int d = 1; d < 64; d <<= 1) s += __shfl_xor(s, d);
  float lw = w - mx - logf(s);  // log_softmax over i

  float mv  = mu[idx];
  float sig = log1pf(expf(ps[idx]));  // jax.nn.softplus
  float inv2 = 1.0f / (sig * sig);
  float A = -0.5f * inv2 * kLog2e;
  float B = mv * inv2 * kLog2e;
  float C = (lw - logf(sig) - kHalfLog2Pi - 0.5f * mv * mv * inv2) * kLog2e;

  float* base = P + (size_t)(m * TTG_K + j) * 192;
  base[i]       = A;
  base[64 + i]  = B;
  base[128 + i] = C;
}

// ---------------- main chain kernel ----------------
// Block: 512 threads (8 waves), 64 samples. Wave w owns sample groups 2w, 2w+1
// (4 samples each). Lane = output row i. u kept in LDS as [grp][j][4 samples]
// so the j-loop u read is a uniform ds_read_b128 broadcast; params staged in
// LDS transposed so lane-i reads are conflict-free consecutive dwords.
__global__ __launch_bounds__(512, 4) void ttg_main(
    const float* __restrict__ X, const float* __restrict__ P,
    const float* __restrict__ wk0, float* __restrict__ out) {
  __shared__ __align__(16) float pr[3 * TTG_K * TTG_K];  // 48 KB: [j][plane][i]
  __shared__ __align__(16) float ub[2][16 * TTG_K * 4];  // 2 x 16 KB: [grp][j][c]

  const int tid  = threadIdx.x;
  const int lane = tid & 63;
  const int wv   = __builtin_amdgcn_readfirstlane(tid >> 6);
  const int blk  = blockIdx.x;

  // init u0 = wk0 for all 64 samples
  for (int r = 0; r < 8; ++r) {
    int idx = tid + r * 512;            // 4096 floats
    ub[0][idx] = wk0[(idx >> 2) & 63];  // value depends on j only
  }

  int cur = 0;
  for (int m = 0; m < TTG_M; ++m) {
    __syncthreads();  // prev step done (and u0 init on m==0) before param overwrite
    // stage this step's 48 KB of coefficients: 3072 float4 / 512 threads
    const float4* src = (const float4*)(P + (size_t)m * 12288);
    float4* dst = (float4*)pr;
#pragma unroll
    for (int r = 0; r < 6; ++r) dst[tid + r * 512] = src[tid + r * 512];
    __syncthreads();

#pragma unroll
    for (int g = 0; g < 2; ++g) {
      const int grp = wv * 2 + g;
      const int s0  = blk * 64 + grp * 4;
      // x values are wave-uniform (scalar loads)
      const float x0 = X[(s0 + 0) * TTG_M + m];
      const float x1 = X[(s0 + 1) * TTG_M + m];
      const float x2 = X[(s0 + 2) * TTG_M + m];
      const float x3 = X[(s0 + 3) * TTG_M + m];
      float a0 = 0.f, a1 = 0.f, a2 = 0.f, a3 = 0.f;
      const float4* u4 = (const float4*)&ub[cur][grp * 256];
      const float* prl = pr + lane;
#pragma unroll 4
      for (int j = 0; j < TTG_K; ++j) {
        const float A = prl[j * 192];
        const float B = prl[j * 192 + 64];
        const float C = prl[j * 192 + 128];
        const float4 uj = u4[j];
        float t0 = fmaf(fmaf(A, x0, B), x0, C);
        float t1 = fmaf(fmaf(A, x1, B), x1, C);
        float t2 = fmaf(fmaf(A, x2, B), x2, C);
        float t3 = fmaf(fmaf(A, x3, B), x3, C);
        a0 = fmaf(TTG_EXP2(t0), uj.x, a0);
        a1 = fmaf(TTG_EXP2(t1), uj.y, a1);
        a2 = fmaf(TTG_EXP2(t2), uj.z, a2);
        a3 = fmaf(TTG_EXP2(t3), uj.w, a3);
      }
      ((float4*)&ub[cur ^ 1][grp * 256])[lane] = make_float4(a0, a1, a2, a3);
    }
    cur ^= 1;
  }

  __syncthreads();
  if (tid < 64) {  // one thread per sample: likelihood = sum_j u_M[j]
    const int grp = tid >> 2, c = tid & 3;
    float s = 0.f;
    for (int j = 0; j < TTG_K; ++j) s += ub[cur][grp * 256 + j * 4 + c];
    out[blk * 64 + tid] = logf(s + kEps);
  }
}

extern "C" void kernel_launch(void* const* d_in, const int* in_sizes, int n_in,
                              void* d_out, int out_size, void* d_ws, size_t ws_size,
                              hipStream_t stream) {
  const float* X   = (const float*)d_in[0];  // (N, M)
  const float* wl  = (const float*)d_in[1];  // (1, K)
  const float* W   = (const float*)d_in[2];  // (M, K, K)
  const float* mu  = (const float*)d_in[3];  // (M, K, K)
  const float* ps  = (const float*)d_in[4];  // (M, K, K)
  float* out = (float*)d_out;

  // workspace: [0,256) floats wk0 ; [256, 256+M*K*3*K) floats coefficients
  float* wk0 = (float*)d_ws;
  float* P   = wk0 + 256;  // 16B aligned; needs 786432 B + 1 KB <= ws_size

  ttg_prep_wk0<<<1, 64, 0, stream>>>(wl, wk0);
  ttg_prep_params<<<TTG_M * TTG_K, 64, 0, stream>>>(W, mu, ps, P);
  ttg_main<<<TTG_N / 64, 512, 0, stream>>>(X, P, wk0, out);
}

// Round 3
// 271.992 us; speedup vs baseline: 1.1588x; 1.1588x over previous
//
#include <hip/hip_runtime.h>
#include <math.h>

// TensorTrainGaussian likelihood as a matvec chain:
//   u0 = softmax(wk0_logits); u_{m+1} = R_m(x_n) u_m;  out = log(sum(u_16) + EPS)
//   R_m[i,j] = exp2( (A*x + B)*x + C ),  per-(m,i,j):
// A = -0.5/s^2*log2e, B = mu/s^2*log2e,
// C = (logW - log s - 0.5*log(2pi) - 0.5*mu^2/s^2)*log2e, s = softplus(pre_sigma)
// Coefficients packed as j-parity pairs for v_pk_fma_f32.

#define TTG_N 32768
#define TTG_M 16
#define TTG_K 64

typedef float f32x2 __attribute__((ext_vector_type(2)));

static constexpr float kHalfLog2Pi = 0.9189385332046727f;
static constexpr float kEps        = 2.220446049250313e-16f;
static constexpr float kLog2e      = 1.4426950408889634f;

#if defined(__has_builtin)
#if __has_builtin(__builtin_amdgcn_exp2f)
#define TTG_EXP2(x) __builtin_amdgcn_exp2f(x)
#else
#define TTG_EXP2(x) exp2f(x)
#endif
#else
#define TTG_EXP2(x) exp2f(x)
#endif

// d = {s0.lo * x + s2.lo, s0.hi * x + s2.hi}, x = selected half of xx.
// op_sel picks halves for LOW result, op_sel_hi for HIGH result; order [s0,s1,s2].
#define PK_SEL0(d, s0, xx, s2)                                                \
  asm("v_pk_fma_f32 %0, %1, %2, %3 op_sel:[0,0,0] op_sel_hi:[1,0,1]"          \
      : "=v"(d) : "v"(s0), "v"(xx), "v"(s2))
#define PK_SEL1(d, s0, xx, s2)                                                \
  asm("v_pk_fma_f32 %0, %1, %2, %3 op_sel:[0,1,0] op_sel_hi:[1,1,1]"          \
      : "=v"(d) : "v"(s0), "v"(xx), "v"(s2))

// ---------------- prep: wk0 = softmax(wk0_logits) ----------------
__global__ void ttg_prep_wk0(const float* __restrict__ logits,
                             float* __restrict__ wk0) {
  int i = threadIdx.x;  // 64 threads = 1 wave
  float l = logits[i];
  float mx = l;
  for (int d = 1; d < 64; d <<= 1) mx = fmaxf(mx, __shfl_xor(mx, d));
  float e = expf(l - mx);
  float s = e;
  for (int d = 1; d < 64; d <<= 1) s += __shfl_xor(s, d);
  wk0[i] = e / s;
}

// ---------------- prep: Horner coefficients, j-pair packed ----------------
// One wave per (m, j); lane = i. log_softmax over i (axis=1 of (M,K,K)).
// Per m (12288 floats): A2 [j/2][i][2] @0, B2 @4096, C2 @8192.
__global__ void ttg_prep_params(const float* __restrict__ W,
                                const float* __restrict__ mu,
                                const float* __restrict__ ps,
                                float* __restrict__ P) {
  int b = blockIdx.x;
  int m = b >> 6;
  int j = b & 63;
  int i = threadIdx.x;
  int idx = (m * TTG_K + i) * TTG_K + j;  // [m][i][j]

  float w = W[idx];
  float mx = w;
  for (int d = 1; d < 64; d <<= 1) mx = fmaxf(mx, __shfl_xor(mx, d));
  float e = expf(w - mx);
  float s = e;
  for (int d = 1; d < 64; d <<= 1) s += __shfl_xor(s, d);
  float lw = w - mx - logf(s);  // log_softmax over i

  float mv  = mu[idx];
  float sig = log1pf(expf(ps[idx]));  // jax.nn.softplus
  float inv2 = 1.0f / (sig * sig);
  float A = -0.5f * inv2 * kLog2e;
  float B = mv * inv2 * kLog2e;
  float C = (lw - logf(sig) - kHalfLog2Pi - 0.5f * mv * mv * inv2) * kLog2e;

  float* base = P + (size_t)m * 12288;
  int pi = ((j >> 1) * TTG_K + i) * 2 + (j & 1);
  base[pi]        = A;
  base[4096 + pi] = B;
  base[8192 + pi] = C;
}

// ---------------- main chain kernel ----------------
// 512 threads (8 waves), 64 samples/block; wave w owns samples w*8..w*8+7.
// lane = i. u in LDS transposed [sample][j] so {u_j,u_j+1} is one b64
// broadcast. Params staged in LDS (reg-prefetched, T14); packed Horner via
// op_sel'd v_pk_fma_f32; packed accumulate.
__global__ __launch_bounds__(512, 4) void ttg_main(
    const float* __restrict__ X, const float* __restrict__ P,
    const float* __restrict__ wk0, float* __restrict__ out) {
  __shared__ __align__(16) float prA[TTG_K * TTG_K];  // 16 KB [j/2][i][2]
  __shared__ __align__(16) float prB[TTG_K * TTG_K];  // 16 KB
  __shared__ __align__(16) float prC[TTG_K * TTG_K];  // 16 KB
  __shared__ __align__(16) float ub[64 * TTG_K];      // 16 KB [sample][j]
  __shared__ __align__(16) float xbT[TTG_M * 64];     //  4 KB [m][sample]

  const int tid  = threadIdx.x;
  const int lane = tid & 63;
  const int wv   = __builtin_amdgcn_readfirstlane(tid >> 6);
  const int blk  = blockIdx.x;

  // stage X transposed: xbT[m][s] = X[blk*64+s][m]
  if (tid < 256) {
    float4 v = ((const float4*)X)[blk * 256 + tid];
    int s = tid >> 2, f0 = (tid & 3) * 4;
    xbT[(f0 + 0) * 64 + s] = v.x;
    xbT[(f0 + 1) * 64 + s] = v.y;
    xbT[(f0 + 2) * 64 + s] = v.z;
    xbT[(f0 + 3) * 64 + s] = v.w;
  }
  // u0[s][j] = wk0[j]
#pragma unroll
  for (int r = 0; r < 8; ++r) {
    int idx = tid + r * 512;
    ub[idx] = wk0[idx & 63];
  }
  // stage m=0 params
  {
    const float4* src = (const float4*)P;
#pragma unroll
    for (int r = 0; r < 2; ++r) ((float4*)prA)[tid + r * 512] = src[tid + r * 512];
#pragma unroll
    for (int r = 0; r < 2; ++r) ((float4*)prB)[tid + r * 512] = src[1024 + tid + r * 512];
#pragma unroll
    for (int r = 0; r < 2; ++r) ((float4*)prC)[tid + r * 512] = src[2048 + tid + r * 512];
  }
  __syncthreads();

  float a0, a1, a2s, a3, a4, a5, a6, a7;
  for (int m = 0; m < TTG_M; ++m) {
    // T14: issue next step's param loads now; commit after barrier.
    float4 pf0, pf1, pf2, pf3, pf4, pf5;
    if (m < TTG_M - 1) {
      const float4* src = (const float4*)(P + (size_t)(m + 1) * 12288);
      pf0 = src[tid];
      pf1 = src[tid + 512];
      pf2 = src[tid + 1024];
      pf3 = src[tid + 1536];
      pf4 = src[tid + 2048];
      pf5 = src[tid + 2560];
    }
    // wave-uniform x pairs for this wave's 8 samples
    const f32x2* xrow = (const f32x2*)(xbT + m * 64 + wv * 8);
    const f32x2 xx01 = xrow[0], xx23 = xrow[1], xx45 = xrow[2], xx67 = xrow[3];

    f32x2 acc0 = {0.f, 0.f}, acc1 = acc0, acc2 = acc0, acc3 = acc0;
    f32x2 acc4 = acc0, acc5 = acc0, acc6 = acc0, acc7 = acc0;
    const f32x2* pA = ((const f32x2*)prA) + lane;
    const f32x2* pB = ((const f32x2*)prB) + lane;
    const f32x2* pC = ((const f32x2*)prC) + lane;
    const f32x2* pU = (const f32x2*)(ub + wv * 8 * TTG_K);  // 8 rows of 32 pairs

#define TTG_SAMPLE(SEL, XX, UROW, ACC)                                        \
    {                                                                         \
      const f32x2 u2 = pU[(UROW) * 32 + j2];                                  \
      f32x2 h, t;                                                             \
      SEL(h, a2, XX, b2);                                                     \
      SEL(t, h, XX, c2);                                                      \
      f32x2 e2 = {TTG_EXP2(t[0]), TTG_EXP2(t[1])};                            \
      ACC += e2 * u2;                                                         \
    }

#pragma unroll 2
    for (int j2 = 0; j2 < 32; ++j2) {
      const f32x2 a2 = pA[j2 * 64];  // ds_read_b64, conflict-free
      const f32x2 b2 = pB[j2 * 64];
      const f32x2 c2 = pC[j2 * 64];
      TTG_SAMPLE(PK_SEL0, xx01, 0, acc0)
      TTG_SAMPLE(PK_SEL1, xx01, 1, acc1)
      TTG_SAMPLE(PK_SEL0, xx23, 2, acc2)
      TTG_SAMPLE(PK_SEL1, xx23, 3, acc3)
      TTG_SAMPLE(PK_SEL0, xx45, 4, acc4)
      TTG_SAMPLE(PK_SEL1, xx45, 5, acc5)
      TTG_SAMPLE(PK_SEL0, xx67, 6, acc6)
      TTG_SAMPLE(PK_SEL1, xx67, 7, acc7)
    }
#undef TTG_SAMPLE

    a0 = acc0[0] + acc0[1];
    a1 = acc1[0] + acc1[1];
    a2s = acc2[0] + acc2[1];
    a3 = acc3[0] + acc3[1];
    a4 = acc4[0] + acc4[1];
    a5 = acc5[0] + acc5[1];
    a6 = acc6[0] + acc6[1];
    a7 = acc7[0] + acc7[1];

    if (m < TTG_M - 1) {
      __syncthreads();  // all waves done reading ub/params
      // u_{m+1}[s][i]: lane i writes its row entry for the wave's 8 samples
      float* ud = ub + wv * 8 * TTG_K + lane;
      ud[0 * TTG_K] = a0;
      ud[1 * TTG_K] = a1;
      ud[2 * TTG_K] = a2s;
      ud[3 * TTG_K] = a3;
      ud[4 * TTG_K] = a4;
      ud[5 * TTG_K] = a5;
      ud[6 * TTG_K] = a6;
      ud[7 * TTG_K] = a7;
      // commit prefetched params
      ((float4*)prA)[tid]       = pf0;
      ((float4*)prA)[tid + 512] = pf1;
      ((float4*)prB)[tid]       = pf2;
      ((float4*)prB)[tid + 512] = pf3;
      ((float4*)prC)[tid]       = pf4;
      ((float4*)prC)[tid + 512] = pf5;
      __syncthreads();
    }
  }

  // likelihood_s = sum_i a_s  -> wave shuffle reduce, then log
  float r[8] = {a0, a1, a2s, a3, a4, a5, a6, a7};
#pragma unroll
  for (int c = 0; c < 8; ++c) {
#pragma unroll
    for (int d = 1; d < 64; d <<= 1) r[c] += __shfl_xor(r[c], d);
  }
  if (lane == 0) {
    const int s0 = blk * 64 + wv * 8;
#pragma unroll
    for (int c = 0; c < 8; ++c) out[s0 + c] = logf(r[c] + kEps);
  }
}

extern "C" void kernel_launch(void* const* d_in, const int* in_sizes, int n_in,
                              void* d_out, int out_size, void* d_ws, size_t ws_size,
                              hipStream_t stream) {
  const float* X   = (const float*)d_in[0];  // (N, M)
  const float* wl  = (const float*)d_in[1];  // (1, K)
  const float* W   = (const float*)d_in[2];  // (M, K, K)
  const float* mu  = (const float*)d_in[3];  // (M, K, K)
  const float* ps  = (const float*)d_in[4];  // (M, K, K)
  float* out = (float*)d_out;

  float* wk0 = (float*)d_ws;
  float* P   = wk0 + 256;

  ttg_prep_wk0<<<1, 64, 0, stream>>>(wl, wk0);
  ttg_prep_params<<<TTG_M * TTG_K, 64, 0, stream>>>(W, mu, ps, P);
  ttg_main<<<TTG_N / 64, 512, 0, stream>>>(X, P, wk0, out);
}

// Round 4
// 267.155 us; speedup vs baseline: 1.1797x; 1.0181x over previous
//
#include <hip/hip_runtime.h>
#include <math.h>

// TensorTrainGaussian likelihood as a matvec chain:
//   u0 = softmax(wk0_logits); u_{m+1} = R_m(x_n) u_m;  out = log(sum(u_16) + EPS)
//   R_m[i,j] = exp2( (A*x + B)*x + C ),  per-(m,i,j):
// A = -0.5/s^2*log2e, B = mu/s^2*log2e,
// C = (logW - log s - 0.5*log(2pi) - 0.5*mu^2/s^2)*log2e, s = softplus(pre_sigma)
// Coefficients packed as j-parity pairs; packed Horner via f32x2 elementwise fma.

#define TTG_N 32768
#define TTG_M 16
#define TTG_K 64

typedef float f32x2 __attribute__((ext_vector_type(2)));

static constexpr float kHalfLog2Pi = 0.9189385332046727f;
static constexpr float kEps        = 2.220446049250313e-16f;
static constexpr float kLog2e      = 1.4426950408889634f;

#if defined(__has_builtin)
#if __has_builtin(__builtin_amdgcn_exp2f)
#define TTG_EXP2(x) __builtin_amdgcn_exp2f(x)
#else
#define TTG_EXP2(x) exp2f(x)
#endif
#else
#define TTG_EXP2(x) exp2f(x)
#endif

// ---------------- prep: wk0 = softmax(wk0_logits) ----------------
__global__ void ttg_prep_wk0(const float* __restrict__ logits,
                             float* __restrict__ wk0) {
  int i = threadIdx.x;  // 64 threads = 1 wave
  float l = logits[i];
  float mx = l;
  for (int d = 1; d < 64; d <<= 1) mx = fmaxf(mx, __shfl_xor(mx, d));
  float e = expf(l - mx);
  float s = e;
  for (int d = 1; d < 64; d <<= 1) s += __shfl_xor(s, d);
  wk0[i] = e / s;
}

// ---------------- prep: Horner coefficients, j-pair packed ----------------
// One wave per (m, j); lane = i. log_softmax over i (axis=1 of (M,K,K)).
// Per m (12288 floats): A2 [j/2][i][2] @0, B2 @4096, C2 @8192.
__global__ void ttg_prep_params(const float* __restrict__ W,
                                const float* __restrict__ mu,
                                const float* __restrict__ ps,
                                float* __restrict__ P) {
  int b = blockIdx.x;
  int m = b >> 6;
  int j = b & 63;
  int i = threadIdx.x;
  int idx = (m * TTG_K + i) * TTG_K + j;  // [m][i][j]

  float w = W[idx];
  float mx = w;
  for (int d = 1; d < 64; d <<= 1) mx = fmaxf(mx, __shfl_xor(mx, d));
  float e = expf(w - mx);
  float s = e;
  for (int d = 1; d < 64; d <<= 1) s += __shfl_xor(s, d);
  float lw = w - mx - logf(s);  // log_softmax over i

  float mv  = mu[idx];
  float sig = log1pf(expf(ps[idx]));  // jax.nn.softplus
  float inv2 = 1.0f / (sig * sig);
  float A = -0.5f * inv2 * kLog2e;
  float B = mv * inv2 * kLog2e;
  float C = (lw - logf(sig) - kHalfLog2Pi - 0.5f * mv * mv * inv2) * kLog2e;

  float* base = P + (size_t)m * 12288;
  int pi = ((j >> 1) * TTG_K + i) * 2 + (j & 1);
  base[pi]        = A;
  base[4096 + pi] = B;
  base[8192 + pi] = C;
}

// ---------------- main chain kernel ----------------
// 1024 threads (16 waves), 64 samples/block; wave w owns samples w*4..w*4+3.
// lane = i. 2 blocks/CU (68 KB LDS) -> 32 waves/CU nominal occupancy.
// u in LDS transposed [sample][j]; params staged via register prefetch (T14).
// j2 loop fully unrolled: all ds_read addresses are base + imm offset.
__global__ __launch_bounds__(1024, 8) void ttg_main(
    const float* __restrict__ X, const float* __restrict__ P,
    const float* __restrict__ wk0, float* __restrict__ out) {
  __shared__ __align__(16) float prA[TTG_K * TTG_K];  // 16 KB [j/2][i][2]
  __shared__ __align__(16) float prB[TTG_K * TTG_K];  // 16 KB
  __shared__ __align__(16) float prC[TTG_K * TTG_K];  // 16 KB
  __shared__ __align__(16) float ub[64 * TTG_K];      // 16 KB [sample][j]
  __shared__ __align__(16) float xbT[TTG_M * 64];     //  4 KB [m][sample]

  const int tid  = threadIdx.x;
  const int lane = tid & 63;
  const int wv   = __builtin_amdgcn_readfirstlane(tid >> 6);  // 0..15
  const int blk  = blockIdx.x;

  // stage X transposed: xbT[m][s] = X[blk*64+s][m]
  if (tid < 256) {
    float4 v = ((const float4*)X)[blk * 256 + tid];
    int s = tid >> 2, f0 = (tid & 3) * 4;
    xbT[(f0 + 0) * 64 + s] = v.x;
    xbT[(f0 + 1) * 64 + s] = v.y;
    xbT[(f0 + 2) * 64 + s] = v.z;
    xbT[(f0 + 3) * 64 + s] = v.w;
  }
  // u0[s][j] = wk0[j]
#pragma unroll
  for (int r = 0; r < 4; ++r) {
    int idx = tid + r * 1024;
    ub[idx] = wk0[idx & 63];
  }
  // stage m=0 params (3072 float4 / 1024 threads)
  {
    const float4* src = (const float4*)P;
    ((float4*)prA)[tid] = src[tid];
    ((float4*)prB)[tid] = src[1024 + tid];
    ((float4*)prC)[tid] = src[2048 + tid];
  }
  __syncthreads();

  float aL0, aL1, aL2, aL3, aH0, aH1, aH2, aH3;
  for (int m = 0; m < TTG_M; ++m) {
    // T14: issue next step's param loads now; commit after the barrier.
    float4 pf0, pf1, pf2;
    if (m < TTG_M - 1) {
      const float4* src = (const float4*)(P + (size_t)(m + 1) * 12288);
      pf0 = src[tid];
      pf1 = src[tid + 1024];
      pf2 = src[tid + 2048];
    }
    // wave-uniform x splat pairs for this wave's 4 samples (j2-invariant)
    const float* xr = xbT + m * 64 + wv * 4;
    const f32x2 xs0 = {xr[0], xr[0]};
    const f32x2 xs1 = {xr[1], xr[1]};
    const f32x2 xs2 = {xr[2], xr[2]};
    const f32x2 xs3 = {xr[3], xr[3]};

    aL0 = aL1 = aL2 = aL3 = 0.f;
    aH0 = aH1 = aH2 = aH3 = 0.f;
    const f32x2* pA = ((const f32x2*)prA) + lane;
    const f32x2* pB = ((const f32x2*)prB) + lane;
    const f32x2* pC = ((const f32x2*)prC) + lane;
    const f32x2* pU = (const f32x2*)(ub + wv * 4 * TTG_K);  // 4 rows x 32 pairs

#define TTG_SAMPLE(XS, UROW, AL, AH)                                          \
    {                                                                         \
      const f32x2 u2 = pU[(UROW) * 32 + j2];                                  \
      f32x2 h = __builtin_elementwise_fma(a2, XS, b2);                        \
      f32x2 t = __builtin_elementwise_fma(h, XS, c2);                         \
      AL = fmaf(TTG_EXP2(t[0]), u2[0], AL);                                   \
      AH = fmaf(TTG_EXP2(t[1]), u2[1], AH);                                   \
    }

#pragma unroll
    for (int j2 = 0; j2 < 32; ++j2) {
      const f32x2 a2 = pA[j2 * 64];  // ds_read_b64, imm offset, 2-way (free)
      const f32x2 b2 = pB[j2 * 64];
      const f32x2 c2 = pC[j2 * 64];
      TTG_SAMPLE(xs0, 0, aL0, aH0)
      TTG_SAMPLE(xs1, 1, aL1, aH1)
      TTG_SAMPLE(xs2, 2, aL2, aH2)
      TTG_SAMPLE(xs3, 3, aL3, aH3)
    }
#undef TTG_SAMPLE

    if (m < TTG_M - 1) {
      __syncthreads();  // all waves done reading ub/params
      // u_{m+1}[s][i]: lane i writes its entry for the wave's 4 samples
      float* ud = ub + wv * 4 * TTG_K + lane;
      ud[0 * TTG_K] = aL0 + aH0;
      ud[1 * TTG_K] = aL1 + aH1;
      ud[2 * TTG_K] = aL2 + aH2;
      ud[3 * TTG_K] = aL3 + aH3;
      // commit prefetched params
      ((float4*)prA)[tid] = pf0;
      ((float4*)prB)[tid] = pf1;
      ((float4*)prC)[tid] = pf2;
      __syncthreads();
    }
  }

  // likelihood_s = sum_i -> wave shuffle reduce, then log
  float r[4] = {aL0 + aH0, aL1 + aH1, aL2 + aH2, aL3 + aH3};
#pragma unroll
  for (int c = 0; c < 4; ++c) {
#pragma unroll
    for (int d = 1; d < 64; d <<= 1) r[c] += __shfl_xor(r[c], d);
  }
  if (lane == 0) {
    const int s0 = blk * 64 + wv * 4;
#pragma unroll
    for (int c = 0; c < 4; ++c) out[s0 + c] = logf(r[c] + kEps);
  }
}

extern "C" void kernel_launch(void* const* d_in, const int* in_sizes, int n_in,
                              void* d_out, int out_size, void* d_ws, size_t ws_size,
                              hipStream_t stream) {
  const float* X   = (const float*)d_in[0];  // (N, M)
  const float* wl  = (const float*)d_in[1];  // (1, K)
  const float* W   = (const float*)d_in[2];  // (M, K, K)
  const float* mu  = (const float*)d_in[3];  // (M, K, K)
  const float* ps  = (const float*)d_in[4];  // (M, K, K)
  float* out = (float*)d_out;

  float* wk0 = (float*)d_ws;
  float* P   = wk0 + 256;

  ttg_prep_wk0<<<1, 64, 0, stream>>>(wl, wk0);
  ttg_prep_params<<<TTG_M * TTG_K, 64, 0, stream>>>(W, mu, ps, P);
  ttg_main<<<TTG_N / 64, 1024, 0, stream>>>(X, P, wk0, out);
}